// Round 9
// baseline (149.427 us; speedup 1.0000x reference)
//
#include <hip/hip_runtime.h>
#include <hip/hip_bf16.h>
#include <stdint.h>

// Problem constants (fixed shapes from reference: B=4096, D=256, N=2B)
#define NROWS 8192
#define DDIM  256
#define BT    128                       // square block tile
#define KSTEPS 8                        // 8 K-steps of 32
#define NTILE (NROWS / BT)              // 64 tile-rows
#define NTRI  (NTILE * (NTILE + 1) / 2) // 2080 upper-tri tiles
// TAU = 0.1 -> z = cos/TAU; exp(z-10) = exp2(cos*L2E/TAU - 10*L2E)
// L2E/TAU == 10*L2E == 14.4269504: e = exp2(SCEXP*(cos - 1)), one FMA + one exp.
#define SCEXP 14.4269504088896340736f

typedef __attribute__((ext_vector_type(8))) short short8;
typedef __attribute__((ext_vector_type(4))) float f32x4;

__device__ __forceinline__ unsigned short f2bf(float x) {
  __hip_bfloat16 h = __float2bfloat16(x);
  return *reinterpret_cast<unsigned short*>(&h);
}

// Kernel 1: bf16 concat(f) PRE-NORMALIZED (inv-norm folded into operands so
// the GEMM accumulator is the cosine directly), labels, zero S arrays + out.
__global__ void __launch_bounds__(256)
milnce_prep(const float* __restrict__ feat, const float* __restrict__ pos,
            const int* __restrict__ labels, unsigned short* __restrict__ fb,
            int* __restrict__ lab, float* __restrict__ S_all,
            float* __restrict__ S_pos, float* __restrict__ out) {
  const int wave = threadIdx.x >> 6;
  const int lane = threadIdx.x & 63;
  const int row  = blockIdx.x * 4 + wave;   // 2048 blocks -> 8192 rows

  const float* src = (row < 4096) ? (feat + (size_t)row * DDIM)
                                  : (pos + (size_t)(row - 4096) * DDIM);
  float4 v = ((const float4*)src)[lane];    // 4 contiguous fp32 per lane

  float ss = v.x*v.x + v.y*v.y + v.z*v.z + v.w*v.w;
  #pragma unroll
  for (int m = 1; m < 64; m <<= 1) ss += __shfl_xor(ss, m, 64);  // all lanes get sum
  const float inv = 1.0f / sqrtf(ss);

  ushort4 o;
  o.x = f2bf(v.x * inv); o.y = f2bf(v.y * inv);
  o.z = f2bf(v.z * inv); o.w = f2bf(v.w * inv);
  ((ushort4*)(fb + (size_t)row * DDIM))[lane] = o;

  const int tid = blockIdx.x * 256 + threadIdx.x;
  if (tid < NROWS) {
    lab[tid]   = labels[tid & 4095];  // concat duplicates labels
    S_all[tid] = 0.0f;
    S_pos[tid] = 0.0f;
  }
  if (tid == 0) out[0] = 0.0f;
}

// Kernel 2: fused f@f^T (bf16 MFMA) + exp2 masked sums over UPPER-TRI tiles.
// Round-9 structural change: ZERO-BARRIER, ZERO-LDS K-loop.
//   Evidence: r8 (clean, no spill) still ran at MfmaUtil 11.5% = exactly the
//   MFMA-floor/duration ratio -> 88% stall = the per-K-step barrier convoy
//   (16 waves storm LDS, all lgkm(0)-wait, all MFMA together; m233's ~72%
//   2-phase overhead). fb is 4 MB = L2-resident per XCD, so LDS staging buys
//   nothing. Fix: 128-thr blocks (2 waves; fitted allocator law: VGPR cap =
//   1024/blockWaves -> 512 regs), each wave autonomous: 64x128 output
//   (acc[4][8]=128 regs), A/B fragments loaded global->reg double-buffered
//   (a[2][4], b[2][8]), fully-unrolled kt (all static indices), 12 loads per
//   K-step as imm-offset dwordx4 off 12 per-lane base pointers (zero VALU
//   addressing). Compiler emits exact counted vmcnt before each use. No
//   s_barrier in the loop; LDS = 5 KB epilogue scratch only.
__global__ void __launch_bounds__(128)
milnce_gemm(const unsigned short* __restrict__ fb, const int* __restrict__ lab,
            float* __restrict__ S_all, float* __restrict__ S_pos) {
  __shared__ __align__(16) float2 rowAP[BT * 5];   // [128 rows][4 slots + pad]

  // Diagonal-order tile decode (d = bj - bi): diagonal d has 64-d tiles.
  int t = blockIdx.x, d = 0, rem = NTILE;
  while (t >= rem) { t -= rem; ++d; --rem; }
  const int bi = t, bj = t + d;

  const int tid  = threadIdx.x;
  const int w    = tid >> 6;       // wave 0/1: rows w*64..w*64+63
  const int lane = tid & 63;
  const int quad = lane >> 4;
  const int l15  = lane & 15;
  const int rowBase = bi * BT;
  const int colBase = bj * BT;

  // Per-lane element pointers. MFMA 16x16x32 frag (r1-verified pattern): lane
  // holds row (base + frag*16 + l15), k-octet quad (8 bf16 = 16 B), advancing
  // 64 B per K-step -> all loads are base + imm-offset.
  const unsigned short* aP[4];
  const unsigned short* bP[8];
  #pragma unroll
  for (int mi = 0; mi < 4; ++mi)
    aP[mi] = fb + (size_t)(rowBase + w * 64 + mi * 16 + l15) * DDIM + quad * 8;
  #pragma unroll
  for (int ni = 0; ni < 8; ++ni)
    bP[ni] = fb + (size_t)(colBase + ni * 16 + l15) * DDIM + quad * 8;

  f32x4 acc[4][8];
  #pragma unroll
  for (int i = 0; i < 4; ++i)
    #pragma unroll
    for (int j = 0; j < 8; ++j) acc[i][j] = (f32x4){0.f, 0.f, 0.f, 0.f};

  short8 a[2][4], b[2][8];
  // Prologue: load kt=0 into set 0.
  #pragma unroll
  for (int mi = 0; mi < 4; ++mi) a[0][mi] = *(const short8*)(aP[mi]);
  #pragma unroll
  for (int ni = 0; ni < 8; ++ni) b[0][ni] = *(const short8*)(bP[ni]);

  #pragma unroll
  for (int kt = 0; kt < KSTEPS; ++kt) {
    const int cur = kt & 1, nxt = cur ^ 1;    // compile-time after unroll
    if (kt + 1 < KSTEPS) {
      #pragma unroll
      for (int mi = 0; mi < 4; ++mi)
        a[nxt][mi] = *(const short8*)(aP[mi] + (kt + 1) * 32);
      #pragma unroll
      for (int ni = 0; ni < 8; ++ni)
        b[nxt][ni] = *(const short8*)(bP[ni] + (kt + 1) * 32);
    }
    __builtin_amdgcn_s_setprio(1);
    #pragma unroll
    for (int mi = 0; mi < 4; ++mi)
      #pragma unroll
      for (int ni = 0; ni < 8; ++ni)
        acc[mi][ni] = __builtin_amdgcn_mfma_f32_16x16x32_bf16(a[cur][mi], b[cur][ni], acc[mi][ni], 0, 0, 0);
    __builtin_amdgcn_s_setprio(0);
  }

  // Epilogue. C/D layout (16x16x32): col = lane&15, row = quad*4 + reg.
  // acc is the cosine directly: e = exp2(SCEXP*acc - SCEXP) == exp(z - 10);
  // the -10 shift cancels in log(S_all) - log(S_pos).
  // Diag tiles (bi==bj): full tile computed, mask row==col, col-commit only
  // (within-tile symmetry makes row sums == col sums). Off-diag: every entry
  // commits to S[col] (direct) and S[row] (mirror of the skipped transpose).
  const bool offdiag = (bi != bj);

  int cl[8], colg[8];
  #pragma unroll
  for (int ni = 0; ni < 8; ++ni) {
    colg[ni] = colBase + ni * 16 + l15;
    cl[ni]   = lab[colg[ni]];
  }

  float2 capk[8];
  #pragma unroll
  for (int ni = 0; ni < 8; ++ni) capk[ni] = make_float2(0.f, 0.f);

  #pragma unroll
  for (int mi = 0; mi < 4; ++mi) {
    const int rloc = w * 64 + mi * 16 + quad * 4;   // local row of elem r=0
    const int4 rl4 = *(const int4*)&lab[rowBase + rloc];
    #pragma unroll
    for (int r = 0; r < 4; ++r) {
      const int rl = (r == 0) ? rl4.x : (r == 1) ? rl4.y : (r == 2) ? rl4.z : rl4.w;
      const int rowg = rowBase + rloc + r;
      float sx = 0.f, sy = 0.f;
      #pragma unroll
      for (int ni = 0; ni < 8; ++ni) {
        float e = exp2f(__builtin_fmaf(acc[mi][ni][r], SCEXP, -SCEXP));
        if (!offdiag && rowg == colg[ni]) e = 0.f;   // mask diagonal entries
        float ep = (rl == cl[ni]) ? e : 0.f;
        capk[ni].x += e; capk[ni].y += ep;
        sx += e; sy += ep;
      }
      if (offdiag) {
        // pre-reduce across l15 (masks 4,8): lanes l15<4 hold the partial for
        // their l15-mod-4 class (4 lanes x 8 ni = 32 of the 128 columns).
        sx += __shfl_xor(sx, 4, 64); sx += __shfl_xor(sx, 8, 64);
        sy += __shfl_xor(sy, 4, 64); sy += __shfl_xor(sy, 8, 64);
        if (l15 < 4)
          rowAP[(rloc + r) * 5 + l15] = make_float2(sx, sy);
      }
    }
  }

  // Column commit: quad-reduce (masks 16,32) -> coalesced 16-lane atomics.
  // Both waves add their 64-row partials; atomics accumulate across blocks.
  #pragma unroll
  for (int ni = 0; ni < 8; ++ni) {
    float x = capk[ni].x, y = capk[ni].y;
    x += __shfl_xor(x, 16, 64); x += __shfl_xor(x, 32, 64);
    y += __shfl_xor(y, 16, 64); y += __shfl_xor(y, 32, 64);
    if (quad == 0) {
      atomicAdd(&S_all[colg[ni]], x);
      atomicAdd(&S_pos[colg[ni]], y);
    }
  }

  __syncthreads();

  if (offdiag) {
    // Row commit (mirror contributions): each thread owns one of 128 rows.
    const float2* rp = rowAP + tid * 5;
    float2 c0 = rp[0], c1 = rp[1], c2 = rp[2], c3 = rp[3];
    atomicAdd(&S_all[rowBase + tid], (c0.x + c1.x) + (c2.x + c3.x));
    atomicAdd(&S_pos[rowBase + tid], (c0.y + c1.y) + (c2.y + c3.y));
  }
}

// Kernel 3: loss = sum_i log(S_all[i]) - log(S_pos[i])  (the +10 shifts cancel).
// 32 blocks, one element per thread, one atomic per block; out zeroed by prep.
__global__ void __launch_bounds__(256)
milnce_final(const float* __restrict__ S_all, const float* __restrict__ S_pos,
             float* __restrict__ out) {
  const int i = blockIdx.x * 256 + threadIdx.x;   // 32*256 == NROWS
  float s = logf(S_all[i]) - logf(S_pos[i]);
  #pragma unroll
  for (int m = 1; m < 64; m <<= 1) s += __shfl_xor(s, m, 64);
  __shared__ float red[4];
  if ((threadIdx.x & 63) == 0) red[threadIdx.x >> 6] = s;
  __syncthreads();
  if (threadIdx.x == 0) atomicAdd(out, (red[0] + red[1]) + (red[2] + red[3]));
}

extern "C" void kernel_launch(void* const* d_in, const int* in_sizes, int n_in,
                              void* d_out, int out_size, void* d_ws, size_t ws_size,
                              hipStream_t stream) {
  const float* feat   = (const float*)d_in[0];
  const float* pos    = (const float*)d_in[1];
  const int*   labels = (const int*)d_in[2];

  char* ws = (char*)d_ws;
  unsigned short* fb    = (unsigned short*)ws;                       // 4 MB bf16 normalized concat
  int*            lab   = (int*)  (ws + 4u * 1024 * 1024);           // 32 KB
  float*          S_all = (float*)(ws + 4u * 1024 * 1024 + 32 * 1024);
  float*          S_pos = (float*)(ws + 4u * 1024 * 1024 + 64 * 1024);
  float*          out   = (float*)d_out;

  hipLaunchKernelGGL(milnce_prep, dim3(NROWS / 4), dim3(256), 0, stream,
                     feat, pos, labels, fb, lab, S_all, S_pos, out);
  hipLaunchKernelGGL(milnce_gemm, dim3(NTRI), dim3(128), 0, stream,
                     fb, lab, S_all, S_pos);
  hipLaunchKernelGGL(milnce_final, dim3(32), dim3(256), 0, stream,
                     S_all, S_pos, out);
}